// Round 2
// baseline (389.232 us; speedup 1.0000x reference)
//
#include <hip/hip_runtime.h>
#include <math.h>

// Problem constants (match reference)
#define L_IN   131072
#define L_OUT  65536
#define NC     16
#define NB     32
#define KSZ    5

// Tiling: register-resident windows, no LDS.
#define THREADS 256
#define OPT     8                      // outputs per thread
#define TPR     (L_OUT / OPT)          // 8192 threads per row
#define BPR     (TPR / THREADS)        // 32 blocks per row

// Fast, numerically-stable log_sigmoid(x) = min(x,0) - log(1 + exp(-|x|)).
// __expf/__logf are the HW transcendental paths (v_exp_f32/v_log_f32),
// abs err ~1e-6 — negligible vs fp32 validation tolerance.
__device__ __forceinline__ float logsig(float x) {
    float t = __expf(-fabsf(x));
    return fminf(x, 0.0f) - __logf(1.0f + t);
}

// tanh(a) = 1 - 2/(exp(2a)+1): monotone, saturates to ±1, no NaN at ±inf
// (e=inf -> 1-0; e=0 -> 1-2). __fdividef -> v_rcp_f32 + mul.
__device__ __forceinline__ float fast_tanh(float a) {
    float e = __expf(2.0f * a);
    return 1.0f - __fdividef(2.0f, e + 1.0f);
}

__global__ __launch_bounds__(THREADS) void conv_ls_tanh_kernel(
    const float* __restrict__ x, const float* __restrict__ w,
    const float* __restrict__ bias, float* __restrict__ out)
{
    const int bid = blockIdx.x;
    const int row = bid / BPR;                    // b*NC + c
    const int rb  = bid - row * BPR;
    const int c   = row & (NC - 1);
    const int lt  = rb * THREADS + threadIdx.x;   // [0, 8192) within row

    const float* xr = x + (size_t)row * L_IN;

    // Thread covers outputs [8*lt, 8*lt+7]; window span = x[16*lt-2 .. 16*lt+16]
    // (19 floats). Load 24 floats v[j] = x[ibase + j], ibase = 16*lt-4, as six
    // 16B-aligned float4s (byte offset 64*lt-16 ≡ 0 mod 16).
    const int ibase = 16 * lt - 4;

    float v[24];                                  // fully unrolled -> registers
    if (lt != 0 && lt != TPR - 1) {
        const float4* p = (const float4*)(xr + ibase);
        #pragma unroll
        for (int q = 0; q < 6; ++q) {
            float4 d = p[q];
            v[4*q+0] = d.x; v[4*q+1] = d.y; v[4*q+2] = d.z; v[4*q+3] = d.w;
        }
    } else {
        // Row-edge threads (2 per row): scalar loads with edge clamp.
        #pragma unroll
        for (int j = 0; j < 24; ++j) {
            int g = ibase + j;
            g = min(max(g, 0), L_IN - 1);
            v[j] = xr[g];
        }
    }

    // logsigmoid once per span element (j = 2..20 are the 19 used values)
    #pragma unroll
    for (int j = 2; j <= 20; ++j) v[j] = logsig(v[j]);

    const float w0 = w[c*KSZ+0], w1 = w[c*KSZ+1], w2 = w[c*KSZ+2],
                w3 = w[c*KSZ+3], w4 = w[c*KSZ+4];
    const float bb = bias[c];

    float o[OPT];
    #pragma unroll
    for (int i = 0; i < OPT; ++i) {
        const int s = 2*i + 2;                    // window start within v[]
        float acc = v[s+0]*w0 + v[s+1]*w1 + v[s+2]*w2 + v[s+3]*w3 + v[s+4]*w4;
        o[i] = fast_tanh(acc + bb);
    }

    // 8 consecutive outputs per lane = 2 aligned float4 stores.
    float* op = out + (size_t)row * L_OUT + (size_t)OPT * lt;
    ((float4*)op)[0] = make_float4(o[0], o[1], o[2], o[3]);
    ((float4*)op)[1] = make_float4(o[4], o[5], o[6], o[7]);
}

extern "C" void kernel_launch(void* const* d_in, const int* in_sizes, int n_in,
                              void* d_out, int out_size, void* d_ws, size_t ws_size,
                              hipStream_t stream) {
    const float* x    = (const float*)d_in[0];
    const float* w    = (const float*)d_in[1];
    const float* bias = (const float*)d_in[2];
    float* out        = (float*)d_out;

    const int grid = NB * NC * BPR;               // 32*16*32 = 16384 blocks
    conv_ls_tanh_kernel<<<grid, THREADS, 0, stream>>>(x, w, bias, out);
}